// Round 11
// baseline (151.893 us; speedup 1.0000x reference)
//
#include <hip/hip_runtime.h>
#include <hip/hip_bf16.h>

// GeometricAttention on MI355X (gfx950).
// B=2, T=2048, C=1024, H=16, hd=64, QK-dim=3.
// d_in are float*, d_out is float*. Internally bf16 MFMA (fp32 accumulate).
// R16: GEMM re-tiled 64x128/256thr -> 64x64/128thr (2 waves, wave-tile
//      64x32): 1024 blocks = 4 blocks/CU = 4 independent barrier groups
//      overlapping each other's vmcnt drains (was 2). Per-wave serial path,
//      reads/MFMA ratio (0.75), barrier count (16) and the proven dbuf+
//      __syncthreads protocol are UNCHANGED. qkproj adapted to 128 thr
//      (split-K x2). k_prep / k_attn verbatim from R15 (verified 148.9us).

typedef short bf16x8 __attribute__((ext_vector_type(8)));
typedef float f32x4 __attribute__((ext_vector_type(4)));
typedef __hip_bfloat16 bf16_t;
typedef unsigned int __attribute__((address_space(1))) u32_as1;
typedef unsigned int __attribute__((address_space(3))) u32_as3;

#define T_SEQ 2048
#define NHEAD 16
#define CDIM 1024
#define L2E 1.4426950408889634f

__device__ __forceinline__ void gl_lds16(const void* g, void* l) {
  __builtin_amdgcn_global_load_lds((const u32_as1*)g, (u32_as3*)l, 16, 0, 0);
}

__device__ __forceinline__ f32x4 mfma16(bf16x8 a, bf16x8 b, f32x4 c) {
  return __builtin_amdgcn_mfma_f32_16x16x32_bf16(a, b, c, 0, 0, 0);
}

__device__ __forceinline__ unsigned short f2bf(float f) {
  __hip_bfloat16 h = __float2bfloat16(f);
  return *(unsigned short*)&h;
}

__device__ __forceinline__ float fast_exp2(float x) {
#if __has_builtin(__builtin_amdgcn_exp2f)
  return __builtin_amdgcn_exp2f(x);
#else
  return exp2f(x);
#endif
}

// ---------------- fused prep: cast x -> xb, transpose+cast wv/wq/wk ----------------
// blocks 0..4095: cast (4 float4/thread); 4096..5119: wv; 5120..5183: wq;
// 5184..5247: wk.  (wo transpose lives in the k_attn launch.)
__global__ __launch_bounds__(256) void k_prep(const float* __restrict__ x,
                                              const float* __restrict__ wq,
                                              const float* __restrict__ wk,
                                              const float* __restrict__ wv,
                                              bf16_t* __restrict__ xb,
                                              bf16_t* __restrict__ wqkT,
                                              bf16_t* __restrict__ wvT) {
  __shared__ bf16_t tile[32][33];
  int bid = blockIdx.x, tid = threadIdx.x;
  if (bid < 4096) {
    int i = bid * 256 + tid;
    float4 v = ((const float4*)x)[i];
    ushort4 o;
    o.x = f2bf(v.x); o.y = f2bf(v.y); o.z = f2bf(v.z); o.w = f2bf(v.w);
    ((ushort4*)xb)[i] = o;
    return;
  }
  const float* src; bf16_t* dst; int R, C, bx, by;
  if (bid < 5120)      { int t = bid - 4096; src = wv; dst = wvT;            R = 1024; C = 1024; bx = t & 31; by = t >> 5; }
  else if (bid < 5184) { int t = bid - 5120; src = wq; dst = wqkT;           R = 1024; C = 48;   bx = t & 1;  by = t >> 1; }
  else                 { int t = bid - 5184; src = wk; dst = wqkT + 48*1024; R = 1024; C = 48;   bx = t & 1;  by = t >> 1; }
  int tx = tid & 31, ty = tid >> 5;
  int r0 = by * 32, c0 = bx * 32;
#pragma unroll
  for (int j = 0; j < 32; j += 8) {
    int r = r0 + ty + j, c = c0 + tx;
    if (r < R && c < C) tile[ty + j][tx] = __float2bfloat16(src[(size_t)r * C + c]);
  }
  __syncthreads();
#pragma unroll
  for (int j = 0; j < 32; j += 8) {
    int c = c0 + ty + j, r = r0 + tx;
    if (r < R && c < C) dst[(size_t)c * R + r] = tile[tx][ty + j];
  }
}

// ---------------- fused GEMM (+ optional QK projection), 128 threads ----------------
// GEMM: 64x64 tile, BK=64 (two 32-wide slabs per buffer), double-buffered,
//   stage(k+1) issued before compute(k), one __syncthreads per K-step
//   (16 barriers). 2 waves, wave-tile 64x32: per K-step 12 ds_read_b128 +
//   16 MFMA per wave (same per-wave path as the R8/R10 kernel). 1024 blocks
//   = 4 blocks/CU -> 4 independent barrier groups overlap drains.
// fuse_qk=1: blocks [0,256) run the QK projection (split-K x2, 128 thr),
//   blocks [256,...) run the GEMM.
__global__ __launch_bounds__(128) void k_gemmqk(const bf16_t* __restrict__ A,
                                                const bf16_t* __restrict__ Bt,
                                                void* __restrict__ Cout,
                                                int M, int N, int K, int mode,
                                                int nbx, int fuse_qk,
                                                const bf16_t* __restrict__ xb,
                                                const bf16_t* __restrict__ wqkT,
                                                const float* __restrict__ head_dirs,
                                                const float* __restrict__ scale,
                                                float* __restrict__ Qt,
                                                float* __restrict__ Kt) {
  __shared__ union SMem {
    struct {
      alignas(16) bf16_t A[2][2 * 64 * 32];   // 16 KB
      alignas(16) bf16_t B[2][2 * 64 * 32];   // 16 KB
    } g;
    float red[2][16][96];  // 12 KB
  } sm;
  int tid = threadIdx.x, wave = tid >> 6, lane = tid & 63;
  int g = lane >> 4, li = lane & 15;

  if (fuse_qk && blockIdx.x < 256) {
    // ---- QK projection path (M=4096, N=96, K=1024), split-K x2 ----
    int m0 = blockIdx.x * 16;
    f32x4 acc[6] = {};
    int kb = wave * 512;
    for (int k0 = kb; k0 < kb + 512; k0 += 32) {
      bf16x8 a = *(const bf16x8*)(xb + (size_t)(m0 + li) * 1024 + k0 + g * 8);
#pragma unroll
      for (int nt = 0; nt < 6; ++nt) {
        bf16x8 bb = *(const bf16x8*)(wqkT + (size_t)(nt * 16 + li) * 1024 + k0 + g * 8);
        acc[nt] = mfma16(a, bb, acc[nt]);
      }
    }
#pragma unroll
    for (int nt = 0; nt < 6; ++nt)
#pragma unroll
      for (int r = 0; r < 4; ++r) sm.red[wave][g * 4 + r][nt * 16 + li] = acc[nt][r];
    __syncthreads();
    for (int i = tid; i < 16 * 96; i += 128) {
      int row = i / 96, col = i - (i / 96) * 96;
      float v = sm.red[0][row][col] + sm.red[1][row][col];
      if (col >= 48) {
        int n = col - 48;
        int h = n / 3, c = n - h * 3;
        int mg = m0 + row;
        int bb = mg >> 11, tt = mg & 2047;
        Kt[(((size_t)bb * NHEAD + h) * 3 + c) * T_SEQ + tt] = v;
      } else {
        sm.red[0][row][col] = v;
      }
    }
    __syncthreads();
    for (int i = tid; i < 256; i += 128) {
      int row = i >> 4, h = i & 15;
      float q0 = sm.red[0][row][h * 3 + 0];
      float q1 = sm.red[0][row][h * 3 + 1];
      float q2 = sm.red[0][row][h * 3 + 2];
      float d0 = head_dirs[h * 3 + 0];
      float d1 = head_dirs[h * 3 + 1];
      float d2 = head_dirs[h * 3 + 2];
      float sc = scale[0] * L2E;
      float dot = (q0 * d0 + q1 * d1 + q2 * d2) * L2E;
      int mg = m0 + row;
      int bb = mg >> 11, tt = mg & 2047;
      size_t base = ((size_t)bb * NHEAD + h) * 3 * T_SEQ + tt;
      Qt[base] = sc * q0 + d0 * dot;
      Qt[base + T_SEQ] = sc * q1 + d1 * dot;
      Qt[base + 2 * T_SEQ] = sc * q2 + d2 * dot;
    }
    return;
  }

  // ---- GEMM path: 64x64 tile, 2 waves (wave-tile 64x32) ----
  int gb = blockIdx.x - (fuse_qk ? 256 : 0);
  int bx = gb % nbx, by = gb / nbx;
  int n0 = bx * 64, m0 = by * 64;
  int wn = wave;  // wave 0: cols 0..31, wave 1: cols 32..63

  // Staging: per buffer, A = 2 slabs x (64 rows x 32 k) = 256 chunks/slab;
  // thread covers chunks {tid, 128+tid} per slab (rows tid>>2 and 32+(tid>>2),
  // k-chunk tid&3). Same for B with n-rows. 8 gl_lds16/thread/K-step.
  const bf16_t* gA0 = A + (size_t)(m0 + (tid >> 2)) * K + (tid & 3) * 8;
  const bf16_t* gA1 = A + (size_t)(m0 + 32 + (tid >> 2)) * K + (tid & 3) * 8;
  const bf16_t* gB0 = Bt + (size_t)(n0 + (tid >> 2)) * K + (tid & 3) * 8;
  const bf16_t* gB1 = Bt + (size_t)(n0 + 32 + (tid >> 2)) * K + (tid & 3) * 8;

#define GSTAGE(bufi, kk)                                          \
  {                                                               \
    char* aB = (char*)&sm.g.A[bufi][0];                           \
    char* bB = (char*)&sm.g.B[bufi][0];                           \
    gl_lds16(gA0 + (kk), aB + tid * 16);                          \
    gl_lds16(gA1 + (kk), aB + (128 + tid) * 16);                  \
    gl_lds16(gA0 + (kk) + 32, aB + 4096 + tid * 16);              \
    gl_lds16(gA1 + (kk) + 32, aB + 4096 + (128 + tid) * 16);      \
    gl_lds16(gB0 + (kk), bB + tid * 16);                          \
    gl_lds16(gB1 + (kk), bB + (128 + tid) * 16);                  \
    gl_lds16(gB0 + (kk) + 32, bB + 4096 + tid * 16);              \
    gl_lds16(gB1 + (kk) + 32, bB + 4096 + (128 + tid) * 16);      \
  }

  f32x4 acc[4][2] = {};
  GSTAGE(0, 0);

  for (int k0 = 0; k0 < K; k0 += 64) {
    int cur = (k0 >> 6) & 1;
    __syncthreads();  // drains vmcnt: buf[cur] ready; frees buf[cur^1]
    if (k0 + 64 < K) GSTAGE(cur ^ 1, k0 + 64);
#pragma unroll
    for (int kk = 0; kk < 2; ++kk) {
      bf16x8 af[4], bfr[2];
#pragma unroll
      for (int mt = 0; mt < 4; ++mt)
        af[mt] = *(const bf16x8*)&sm.g.A[cur][kk * 2048 + (mt * 16 + li) * 32 + g * 8];
#pragma unroll
      for (int nt = 0; nt < 2; ++nt)
        bfr[nt] = *(const bf16x8*)&sm.g.B[cur][kk * 2048 + (wn * 32 + nt * 16 + li) * 32 + g * 8];
#pragma unroll
      for (int mt = 0; mt < 4; ++mt)
#pragma unroll
        for (int nt = 0; nt < 2; ++nt)
          acc[mt][nt] = mfma16(af[mt], bfr[nt], acc[mt][nt]);
    }
  }
#undef GSTAGE

#pragma unroll
  for (int mt = 0; mt < 4; ++mt)
#pragma unroll
    for (int nt = 0; nt < 2; ++nt)
#pragma unroll
      for (int r = 0; r < 4; ++r) {
        int m = m0 + mt * 16 + g * 4 + r;
        int n = n0 + wn * 32 + nt * 16 + li;
        float v = acc[mt][nt][r];
        if (mode == 0) {
          int bb = n >> 11, tt = n & 2047;
          ((bf16_t*)Cout)[((size_t)bb * 1024 + m) * T_SEQ + tt] = __float2bfloat16(v);
        } else {
          ((float*)Cout)[(size_t)m * N + n] = v;
        }
      }
}

// ---------------- attention (+ wo transpose in tail blocks) ----------------
// blocks 0..1023: attention, VERBATIM R14 hot path.
// blocks 1024..2047: wo transpose (woT consumed only by gemm2).
// attn: block = 256 thr (4 waves), one (b,h) x 64-query tile; wave = 16 q.
// KVBLK=128, V staged global->LDS async (XOR-swizzled chunks), K staged
// once per block, exp2-domain scores, double-buffered, 1 barrier/128 keys.
// Rowsums via ones B-frag. Balanced qt map. setprio(1) on PV MFMA cluster.
__global__ __launch_bounds__(256, 4) void k_attn(const float* __restrict__ Qt,
                                                 const float* __restrict__ Kt,
                                                 const bf16_t* __restrict__ VT,
                                                 bf16_t* __restrict__ att,
                                                 const float* __restrict__ wo,
                                                 bf16_t* __restrict__ woT) {
  __shared__ alignas(16) bf16_t Vb[2][2][64 * 64];  // [buf][sub] = 32 KB
  __shared__ alignas(16) float Ks[2][3 * 128];      // [buf] 3 KB
  __shared__ bf16_t trt[32][33];                    // transpose path only
  int tid = threadIdx.x, wave = tid >> 6, lane = tid & 63;
  int g = lane >> 4, li = lane & 15;
  int bid = blockIdx.x;

  if (bid >= 1024) {
    // ---- wo transpose path ----
    int t = bid - 1024;
    int bx = t & 31, by = t >> 5;
    int tx = tid & 31, ty = tid >> 5;
    int r0 = by * 32, c0 = bx * 32;
#pragma unroll
    for (int j = 0; j < 32; j += 8)
      trt[ty + j][tx] = __float2bfloat16(wo[(size_t)(r0 + ty + j) * 1024 + c0 + tx]);
    __syncthreads();
#pragma unroll
    for (int j = 0; j < 32; j += 8)
      woT[(size_t)(c0 + ty + j) * 1024 + r0 + tx] = trt[tx][ty + j];
    return;
  }

  int p = bid >> 5, bh = bid & 31;
  int a = p & 7, bq = p >> 3;
  int qt = (bq == 0) ? a : (bq == 1) ? 31 - a : (bq == 2) ? 8 + a : 23 - a;
  int b = bh >> 4, h = bh & 15;
  int mw = wave * 16;

  const float* Qp = Qt + (size_t)bh * 3 * T_SEQ;
  const float* Kp = Kt + (size_t)bh * 3 * T_SEQ;
  const bf16_t* Vp = VT + (size_t)bh * 64 * T_SEQ;

  int tq = qt * 64 + mw + li;
  float q0 = Qp[tq], q1 = Qp[T_SEQ + tq], q2 = Qp[2 * T_SEQ + tq];

  bf16x8 bones;  // B[n=li][k]=1 iff li==0 -> D[:,0] = rowsum
  unsigned short ob = (li == 0) ? (unsigned short)0x3F80 : (unsigned short)0;
#pragma unroll
  for (int j = 0; j < 8; ++j) bones[j] = (short)ob;

  // per-thread global V chunk pointers (chunk swizzle on the global side):
  // phys chunk P = p*256 + wave*64 + lane -> row d=P>>3, phys c=P&7,
  // logical chunk = (P&7) ^ (d&7); global addr = row d, chunk logical.
  const bf16_t* vg[2];
#pragma unroll
  for (int pp = 0; pp < 2; ++pp) {
    int P = pp * 256 + wave * 64 + lane;
    int d = P >> 3, c = (P & 7) ^ (d & 7);
    vg[pp] = Vp + (size_t)d * T_SEQ + c * 8;
  }
  // K tile staging: 3 rows x 128 f32 = 96 chunks of 16B.
  // wave 3: chunks lane (0..63); wave 2: chunks 32+lane (32..95).
  // Overlap chunks 32..63 written by both with identical data (benign).
  int kch = (wave == 3) ? lane : 32 + lane;
  const float* kg = Kp + (size_t)(kch >> 5) * T_SEQ + (kch & 31) * 4;
  int kbase = (wave == 3) ? 0 : 512;

#define STAGE(bufi, s0v)                                                      \
  {                                                                           \
    _Pragma("unroll") for (int sub_ = 0; sub_ < 2; ++sub_)                    \
        _Pragma("unroll") for (int p_ = 0; p_ < 2; ++p_)                      \
            gl_lds16(vg[p_] + (s0v) + sub_ * 64,                              \
                     (char*)&Vb[bufi][sub_][0] + (p_ * 256 + wave * 64) * 16);\
    if (wave >= 2) gl_lds16(kg + (s0v), (char*)&Ks[bufi][0] + kbase);         \
  }

#define BUILD_AFRAG(MASKED)                                                   \
  _Pragma("unroll") for (int half = 0; half < 2; ++half) {                    \
    int kb = sub * 64 + half * 32 + g * 8;                                    \
    f32x4 kv[3][2];                                                           \
    _Pragma("unroll") for (int c = 0; c < 3; ++c) {                           \
      kv[c][0] = *(const f32x4*)(ks + c * 128 + kb);                          \
      kv[c][1] = *(const f32x4*)(ks + c * 128 + kb + 4);                      \
    }                                                                         \
    _Pragma("unroll") for (int j = 0; j < 8; ++j) {                           \
      float scv = q0 * kv[0][j >> 2][j & 3] + q1 * kv[1][j >> 2][j & 3] +     \
                  q2 * kv[2][j >> 2][j & 3];                                  \
      float pv = fast_exp2(fminf(scv, 115.4f));                               \
      if (MASKED && (bkg + half * 32 + g * 8 + j > tq)) pv = 0.0f;            \
      afrag[half][j] = (short)f2bf(pv);                                       \
    }                                                                         \
  }

  int NT = (qt + 2) >> 1;  // ceil((qt+1)/2) 128-key tiles
  STAGE(0, 0);

  f32x4 acc[5] = {};
  int sw = li & 7;
  int qmin = qt * 64 + mw;
  int qmax = qmin + 15;

  for (int st = 0; st < NT; ++st) {
    int buf = st & 1;
    __syncthreads();  // drains vmcnt (tile st ready) + frees buf^1
    if (st + 1 < NT) STAGE(buf ^ 1, (st + 1) * 128);
    const float* ks = &Ks[buf][0];
#pragma unroll
    for (int sub = 0; sub < 2; ++sub) {
      int bkg = st * 128 + sub * 64;
      if (bkg > qmax) continue;  // sub-tile fully beyond this wave's queries
      bf16x8 afrag[2];
      if (bkg + 63 > qmin) { BUILD_AFRAG(1) } else { BUILD_AFRAG(0) }
      const bf16_t* vb = &Vb[buf][sub][0];
      __builtin_amdgcn_s_setprio(1);
#pragma unroll
      for (int nt = 0; nt < 4; ++nt) {
        int row = nt * 16 + li;
        bf16x8 b0 = *(const bf16x8*)&vb[row * 64 + (g ^ sw) * 8];
        bf16x8 b1 = *(const bf16x8*)&vb[row * 64 + ((4 + g) ^ sw) * 8];
        acc[nt] = mfma16(afrag[0], b0, acc[nt]);
        acc[nt] = mfma16(afrag[1], b1, acc[nt]);
      }
      acc[4] = mfma16(afrag[0], bones, acc[4]);
      acc[4] = mfma16(afrag[1], bones, acc[4]);
      __builtin_amdgcn_s_setprio(0);
    }
  }
#undef STAGE
#undef BUILD_AFRAG

  float linv[4];
#pragma unroll
  for (int r = 0; r < 4; ++r)
    linv[r] = 1.0f / fmaxf(__shfl(acc[4][r], lane & 48), 1e-35f);

#pragma unroll
  for (int nt = 0; nt < 4; ++nt)
#pragma unroll
    for (int r = 0; r < 4; ++r) {
      int t = qt * 64 + mw + g * 4 + r;
      att[((size_t)b * T_SEQ + t) * CDIM + h * 64 + nt * 16 + li] =
          __float2bfloat16(acc[nt][r] * linv[r]);
    }
}

// ---------------- launch ----------------
extern "C" void kernel_launch(void* const* d_in, const int* in_sizes, int n_in,
                              void* d_out, int out_size, void* d_ws, size_t ws_size,
                              hipStream_t stream) {
  const float* x  = (const float*)d_in[0];
  const float* wq = (const float*)d_in[1];
  const float* wk = (const float*)d_in[2];
  const float* wv = (const float*)d_in[3];
  const float* wo = (const float*)d_in[4];
  const float* hd = (const float*)d_in[5];
  const float* sc = (const float*)d_in[6];
  float* out = (float*)d_out;

  char* ws = (char*)d_ws;
  bf16_t* wqkT = (bf16_t*)(ws + 0);          // 96*1024*2      = 196608
  bf16_t* wvT  = (bf16_t*)(ws + 196608);     // 1024*1024*2    = 2097152
  bf16_t* woT  = (bf16_t*)(ws + 2293760);    // 1024*1024*2
  float*  Qt   = (float*)(ws + 4390912);     // 3*32*2048*4    = 786432
  float*  Kt   = (float*)(ws + 5177344);     // 786432
  bf16_t* VT   = (bf16_t*)(ws + 5963776);    // 32*64*2048*2   = 8388608
  bf16_t* att  = (bf16_t*)(ws + 14352384);   // 4096*1024*2    = 8388608
  bf16_t* xb   = (bf16_t*)(ws + 22740992);   // 4096*1024*2    = 8388608

  k_prep<<<5248, 256, 0, stream>>>(x, wq, wk, wv, xb, wqkT, wvT);

  // blocks 0..255: QK projection; blocks 256..1279: VT GEMM (64x64 tiles)
  // VT[vdim][b,t] = sum_k wvT[vdim][k] * xb[b,t][k]
  k_gemmqk<<<1280, 128, 0, stream>>>(wvT, xb, VT, 1024, 4096, 1024, 0, 64, 1,
                                     xb, wqkT, hd, sc, Qt, Kt);

  // blocks 0..1023: attention; blocks 1024..2047: wo transpose (for gemm2)
  k_attn<<<2048, 256, 0, stream>>>(Qt, Kt, VT, att, wo, woT);

  // out = att @ wo (fp32 out)
  k_gemmqk<<<1024, 128, 0, stream>>>(att, woT, out, 4096, 1024, 1024, 1, 16, 0,
                                     nullptr, nullptr, nullptr, nullptr, nullptr, nullptr);
}

// Round 12
// 148.483 us; speedup vs baseline: 1.0230x; 1.0230x over previous
//
#include <hip/hip_runtime.h>
#include <hip/hip_bf16.h>

// GeometricAttention on MI355X (gfx950).
// B=2, T=2048, C=1024, H=16, hd=64, QK-dim=3.
// d_in are float*, d_out is float*. Internally bf16 MFMA (fp32 accumulate).
// R17: R16's 64x64 GEMM reverted (A refetch doubled -> +3us); GEMM back to
//      R15's 64x128/256thr (verified best). New: attn KVBLK 128->64 to cut
//      LDS 35->20KB -> 6 blocks/CU (24 waves, +50% TLP) via
//      __launch_bounds__(256,6). R12 proved barrier count is free (halving
//      was null), so doubling barriers to buy occupancy attacks the real
//      limiter: 52% VALUBusy at 16 waves/CU. Protocol/masks/swizzle same.

typedef short bf16x8 __attribute__((ext_vector_type(8)));
typedef float f32x4 __attribute__((ext_vector_type(4)));
typedef __hip_bfloat16 bf16_t;
typedef unsigned int __attribute__((address_space(1))) u32_as1;
typedef unsigned int __attribute__((address_space(3))) u32_as3;

#define T_SEQ 2048
#define NHEAD 16
#define CDIM 1024
#define L2E 1.4426950408889634f

__device__ __forceinline__ void gl_lds16(const void* g, void* l) {
  __builtin_amdgcn_global_load_lds((const u32_as1*)g, (u32_as3*)l, 16, 0, 0);
}

__device__ __forceinline__ f32x4 mfma16(bf16x8 a, bf16x8 b, f32x4 c) {
  return __builtin_amdgcn_mfma_f32_16x16x32_bf16(a, b, c, 0, 0, 0);
}

__device__ __forceinline__ unsigned short f2bf(float f) {
  __hip_bfloat16 h = __float2bfloat16(f);
  return *(unsigned short*)&h;
}

__device__ __forceinline__ float fast_exp2(float x) {
#if __has_builtin(__builtin_amdgcn_exp2f)
  return __builtin_amdgcn_exp2f(x);
#else
  return exp2f(x);
#endif
}

// ---------------- fused prep: cast x -> xb, transpose+cast wv/wq/wk ----------------
// blocks 0..4095: cast (4 float4/thread); 4096..5119: wv; 5120..5183: wq;
// 5184..5247: wk.  (wo transpose lives in the k_attn launch.)
__global__ __launch_bounds__(256) void k_prep(const float* __restrict__ x,
                                              const float* __restrict__ wq,
                                              const float* __restrict__ wk,
                                              const float* __restrict__ wv,
                                              bf16_t* __restrict__ xb,
                                              bf16_t* __restrict__ wqkT,
                                              bf16_t* __restrict__ wvT) {
  __shared__ bf16_t tile[32][33];
  int bid = blockIdx.x, tid = threadIdx.x;
  if (bid < 4096) {
    int i = bid * 256 + tid;
    float4 v = ((const float4*)x)[i];
    ushort4 o;
    o.x = f2bf(v.x); o.y = f2bf(v.y); o.z = f2bf(v.z); o.w = f2bf(v.w);
    ((ushort4*)xb)[i] = o;
    return;
  }
  const float* src; bf16_t* dst; int R, C, bx, by;
  if (bid < 5120)      { int t = bid - 4096; src = wv; dst = wvT;            R = 1024; C = 1024; bx = t & 31; by = t >> 5; }
  else if (bid < 5184) { int t = bid - 5120; src = wq; dst = wqkT;           R = 1024; C = 48;   bx = t & 1;  by = t >> 1; }
  else                 { int t = bid - 5184; src = wk; dst = wqkT + 48*1024; R = 1024; C = 48;   bx = t & 1;  by = t >> 1; }
  int tx = tid & 31, ty = tid >> 5;
  int r0 = by * 32, c0 = bx * 32;
#pragma unroll
  for (int j = 0; j < 32; j += 8) {
    int r = r0 + ty + j, c = c0 + tx;
    if (r < R && c < C) tile[ty + j][tx] = __float2bfloat16(src[(size_t)r * C + c]);
  }
  __syncthreads();
#pragma unroll
  for (int j = 0; j < 32; j += 8) {
    int c = c0 + ty + j, r = r0 + tx;
    if (r < R && c < C) dst[(size_t)c * R + r] = tile[tx][ty + j];
  }
}

// ---------------- fused GEMM (+ optional QK projection) ----------------
// GEMM: 64x128x64 tile, double-buffered LDS (two 32-wide slabs per buffer),
//   stage(k+1) issued before compute(k), one __syncthreads per K-step
//   (16 barriers). Identical to the R8/R10/R15 harness-verified loop.
// fuse_qk=1: blocks [0,256) run the QK projection (reads xb/wqkT, writes
//   Qt/Kt pre-scaled by log2e), blocks [256,...) run the GEMM.
__global__ __launch_bounds__(256) void k_gemmqk(const bf16_t* __restrict__ A,
                                                const bf16_t* __restrict__ Bt,
                                                void* __restrict__ Cout,
                                                int M, int N, int K, int mode,
                                                int nbx, int fuse_qk,
                                                const bf16_t* __restrict__ xb,
                                                const bf16_t* __restrict__ wqkT,
                                                const float* __restrict__ head_dirs,
                                                const float* __restrict__ scale,
                                                float* __restrict__ Qt,
                                                float* __restrict__ Kt) {
  __shared__ union SMem {
    struct {
      alignas(16) bf16_t A[2][2 * 64 * 32];   // 16 KB
      alignas(16) bf16_t B[2][2 * 128 * 32];  // 32 KB
    } g;
    float red[4][16][96];  // 24 KB
  } sm;
  int tid = threadIdx.x, wave = tid >> 6, lane = tid & 63;
  int g = lane >> 4, li = lane & 15;

  if (fuse_qk && blockIdx.x < 256) {
    // ---- QK projection path (M=4096, N=96, K=1024), split-K x4 ----
    int m0 = blockIdx.x * 16;
    f32x4 acc[6] = {};
    int kb = wave * 256;
    for (int k0 = kb; k0 < kb + 256; k0 += 32) {
      bf16x8 a = *(const bf16x8*)(xb + (size_t)(m0 + li) * 1024 + k0 + g * 8);
#pragma unroll
      for (int nt = 0; nt < 6; ++nt) {
        bf16x8 bb = *(const bf16x8*)(wqkT + (size_t)(nt * 16 + li) * 1024 + k0 + g * 8);
        acc[nt] = mfma16(a, bb, acc[nt]);
      }
    }
#pragma unroll
    for (int nt = 0; nt < 6; ++nt)
#pragma unroll
      for (int r = 0; r < 4; ++r) sm.red[wave][g * 4 + r][nt * 16 + li] = acc[nt][r];
    __syncthreads();
    for (int i = tid; i < 16 * 96; i += 256) {
      int row = i / 96, col = i - (i / 96) * 96;
      float v = sm.red[0][row][col] + sm.red[1][row][col] + sm.red[2][row][col] + sm.red[3][row][col];
      if (col >= 48) {
        int n = col - 48;
        int h = n / 3, c = n - h * 3;
        int mg = m0 + row;
        int bb = mg >> 11, tt = mg & 2047;
        Kt[(((size_t)bb * NHEAD + h) * 3 + c) * T_SEQ + tt] = v;
      } else {
        sm.red[0][row][col] = v;
      }
    }
    __syncthreads();
    int row = tid >> 4, h = tid & 15;
    float q0 = sm.red[0][row][h * 3 + 0];
    float q1 = sm.red[0][row][h * 3 + 1];
    float q2 = sm.red[0][row][h * 3 + 2];
    float d0 = head_dirs[h * 3 + 0];
    float d1 = head_dirs[h * 3 + 1];
    float d2 = head_dirs[h * 3 + 2];
    float sc = scale[0] * L2E;
    float dot = (q0 * d0 + q1 * d1 + q2 * d2) * L2E;
    int mg = m0 + row;
    int bb = mg >> 11, tt = mg & 2047;
    size_t base = ((size_t)bb * NHEAD + h) * 3 * T_SEQ + tt;
    Qt[base] = sc * q0 + d0 * dot;
    Qt[base + T_SEQ] = sc * q1 + d1 * dot;
    Qt[base + 2 * T_SEQ] = sc * q2 + d2 * dot;
    return;
  }

  // ---- GEMM path (R8/R10-verified double-buffered loop) ----
  int gb = blockIdx.x - (fuse_qk ? 256 : 0);
  int bx = gb % nbx, by = gb / nbx;
  int n0 = bx * 128, m0 = by * 64;
  int wm = wave >> 1, wn = wave & 1;

  const bf16_t* gA0 = A + (size_t)(m0 + (tid >> 2)) * K + (tid & 3) * 8;
  const bf16_t* gB0 = Bt + (size_t)(n0 + (tid >> 2)) * K + (tid & 3) * 8;
  const bf16_t* gB1 = Bt + (size_t)(n0 + 64 + (tid >> 2)) * K + (tid & 3) * 8;

#define GSTAGE(bufi, kk)                                          \
  {                                                               \
    char* aB = (char*)&sm.g.A[bufi][0];                           \
    char* bB = (char*)&sm.g.B[bufi][0];                           \
    gl_lds16(gA0 + (kk), aB + tid * 16);                          \
    gl_lds16(gA0 + (kk) + 32, aB + (256 + tid) * 16);             \
    gl_lds16(gB0 + (kk), bB + tid * 16);                          \
    gl_lds16(gB1 + (kk), bB + (256 + tid) * 16);                  \
    gl_lds16(gB0 + (kk) + 32, bB + (512 + tid) * 16);             \
    gl_lds16(gB1 + (kk) + 32, bB + (768 + tid) * 16);             \
  }

  f32x4 acc[2][4] = {};
  GSTAGE(0, 0);

  for (int k0 = 0; k0 < K; k0 += 64) {
    int cur = (k0 >> 6) & 1;
    __syncthreads();  // drains vmcnt: buf[cur] ready; frees buf[cur^1]
    if (k0 + 64 < K) GSTAGE(cur ^ 1, k0 + 64);
#pragma unroll
    for (int kk = 0; kk < 2; ++kk) {
      bf16x8 af[2], bfr[4];
#pragma unroll
      for (int mt = 0; mt < 2; ++mt)
        af[mt] = *(const bf16x8*)&sm.g.A[cur][kk * 2048 + (wm * 32 + mt * 16 + li) * 32 + g * 8];
#pragma unroll
      for (int nt = 0; nt < 4; ++nt)
        bfr[nt] = *(const bf16x8*)&sm.g.B[cur][kk * 4096 + (wn * 64 + nt * 16 + li) * 32 + g * 8];
#pragma unroll
      for (int mt = 0; mt < 2; ++mt)
#pragma unroll
        for (int nt = 0; nt < 4; ++nt)
          acc[mt][nt] = mfma16(af[mt], bfr[nt], acc[mt][nt]);
    }
  }
#undef GSTAGE

#pragma unroll
  for (int mt = 0; mt < 2; ++mt)
#pragma unroll
    for (int nt = 0; nt < 4; ++nt)
#pragma unroll
      for (int r = 0; r < 4; ++r) {
        int m = m0 + wm * 32 + mt * 16 + g * 4 + r;
        int n = n0 + wn * 64 + nt * 16 + li;
        float v = acc[mt][nt][r];
        if (mode == 0) {
          int bb = n >> 11, tt = n & 2047;
          ((bf16_t*)Cout)[((size_t)bb * 1024 + m) * T_SEQ + tt] = __float2bfloat16(v);
        } else {
          ((float*)Cout)[(size_t)m * N + n] = v;
        }
      }
}

// ---------------- attention (+ wo transpose in tail blocks) ----------------
// blocks 0..1023: attention; blocks 1024..2047: wo transpose (for gemm2).
// attn: block = 256 thr (4 waves), one (b,h) x 64-query tile; wave = 16 q.
// KVBLK=64: one 64-key tile per barrier; LDS = Vb 16KB + Ks 1.5KB -> 6
// blocks/CU (launch_bounds(256,6)) = 24 waves/CU (+50% TLP vs KVBLK=128).
// V staged global->LDS async (XOR-swizzled chunks, 2/thread), K staged by
// wave 3 (48 chunks). exp2-domain scores, double-buffered, rowsums via
// ones B-frag, balanced qt map, setprio(1) on PV MFMA cluster.
__global__ __launch_bounds__(256, 6) void k_attn(const float* __restrict__ Qt,
                                                 const float* __restrict__ Kt,
                                                 const bf16_t* __restrict__ VT,
                                                 bf16_t* __restrict__ att,
                                                 const float* __restrict__ wo,
                                                 bf16_t* __restrict__ woT) {
  __shared__ alignas(16) bf16_t Vb[2][64 * 64];  // [buf] 16 KB
  __shared__ alignas(16) float Ks[2][3 * 64];    // [buf] 1.5 KB
  __shared__ bf16_t trt[32][33];                 // transpose path only
  int tid = threadIdx.x, wave = tid >> 6, lane = tid & 63;
  int g = lane >> 4, li = lane & 15;
  int bid = blockIdx.x;

  if (bid >= 1024) {
    // ---- wo transpose path ----
    int t = bid - 1024;
    int bx = t & 31, by = t >> 5;
    int tx = tid & 31, ty = tid >> 5;
    int r0 = by * 32, c0 = bx * 32;
#pragma unroll
    for (int j = 0; j < 32; j += 8)
      trt[ty + j][tx] = __float2bfloat16(wo[(size_t)(r0 + ty + j) * 1024 + c0 + tx]);
    __syncthreads();
#pragma unroll
    for (int j = 0; j < 32; j += 8)
      woT[(size_t)(c0 + ty + j) * 1024 + r0 + tx] = trt[tx][ty + j];
    return;
  }

  int p = bid >> 5, bh = bid & 31;
  int a = p & 7, bq = p >> 3;
  int qt = (bq == 0) ? a : (bq == 1) ? 31 - a : (bq == 2) ? 8 + a : 23 - a;
  int b = bh >> 4, h = bh & 15;
  int mw = wave * 16;

  const float* Qp = Qt + (size_t)bh * 3 * T_SEQ;
  const float* Kp = Kt + (size_t)bh * 3 * T_SEQ;
  const bf16_t* Vp = VT + (size_t)bh * 64 * T_SEQ;

  int tq = qt * 64 + mw + li;
  float q0 = Qp[tq], q1 = Qp[T_SEQ + tq], q2 = Qp[2 * T_SEQ + tq];

  bf16x8 bones;  // B[n=li][k]=1 iff li==0 -> D[:,0] = rowsum
  unsigned short ob = (li == 0) ? (unsigned short)0x3F80 : (unsigned short)0;
#pragma unroll
  for (int j = 0; j < 8; ++j) bones[j] = (short)ob;

  // per-thread global V chunk pointers (chunk swizzle on the global side):
  // 64-key tile = 64 d-rows x 8 chunks = 512 chunks; thread covers
  // P = p*256 + wave*64 + lane (p=0,1): row d=P>>3, phys slot P&7,
  // logical chunk = (P&7) ^ (d&7); global addr = row d, logical chunk.
  const bf16_t* vg[2];
  int vofs[2];
#pragma unroll
  for (int pp = 0; pp < 2; ++pp) {
    int P = pp * 256 + wave * 64 + lane;
    int d = P >> 3, c = (P & 7) ^ (d & 7);
    vg[pp] = Vp + (size_t)d * T_SEQ + c * 8;
    vofs[pp] = P * 16;
  }
  // K tile staging: 3 rows x 64 f32 = 48 chunks of 16B; wave 3, lane<48:
  // chunk lane -> row lane>>4, col (lane&15)*4.
  const float* kg = Kp + (size_t)(lane >> 4) * T_SEQ + (lane & 15) * 4;

#define STAGE(bufi, s0v)                                                      \
  {                                                                           \
    gl_lds16(vg[0] + (s0v), (char*)&Vb[bufi][0] + vofs[0]);                   \
    gl_lds16(vg[1] + (s0v), (char*)&Vb[bufi][0] + vofs[1]);                   \
    if (wave == 3 && lane < 48)                                               \
      gl_lds16(kg + (s0v), (char*)&Ks[bufi][0] + lane * 16);                  \
  }

#define BUILD_AFRAG(MASKED)                                                   \
  _Pragma("unroll") for (int half = 0; half < 2; ++half) {                    \
    int kb = half * 32 + g * 8;                                               \
    f32x4 kv[3][2];                                                           \
    _Pragma("unroll") for (int c = 0; c < 3; ++c) {                           \
      kv[c][0] = *(const f32x4*)(ks + c * 64 + kb);                           \
      kv[c][1] = *(const f32x4*)(ks + c * 64 + kb + 4);                       \
    }                                                                         \
    _Pragma("unroll") for (int j = 0; j < 8; ++j) {                           \
      float scv = q0 * kv[0][j >> 2][j & 3] + q1 * kv[1][j >> 2][j & 3] +     \
                  q2 * kv[2][j >> 2][j & 3];                                  \
      float pv = fast_exp2(fminf(scv, 115.4f));                               \
      if (MASKED && (bkg + half * 32 + g * 8 + j > tq)) pv = 0.0f;            \
      afrag[half][j] = (short)f2bf(pv);                                       \
    }                                                                         \
  }

  int NT = qt + 1;  // 64-key tiles
  STAGE(0, 0);

  f32x4 acc[5] = {};
  int sw = li & 7;

  for (int st = 0; st < NT; ++st) {
    int buf = st & 1;
    __syncthreads();  // drains vmcnt (tile st ready) + frees buf^1
    if (st + 1 < NT) STAGE(buf ^ 1, (st + 1) * 64);
    const float* ks = &Ks[buf][0];
    int bkg = st * 64;
    bf16x8 afrag[2];
    if (st == qt) { BUILD_AFRAG(1) } else { BUILD_AFRAG(0) }
    const bf16_t* vb = &Vb[buf][0];
    __builtin_amdgcn_s_setprio(1);
#pragma unroll
    for (int nt = 0; nt < 4; ++nt) {
      int row = nt * 16 + li;
      bf16x8 b0 = *(const bf16x8*)&vb[row * 64 + (g ^ sw) * 8];
      bf16x8 b1 = *(const bf16x8*)&vb[row * 64 + ((4 + g) ^ sw) * 8];
      acc[nt] = mfma16(afrag[0], b0, acc[nt]);
      acc[nt] = mfma16(afrag[1], b1, acc[nt]);
    }
    acc[4] = mfma16(afrag[0], bones, acc[4]);
    acc[4] = mfma16(afrag[1], bones, acc[4]);
    __builtin_amdgcn_s_setprio(0);
  }
#undef STAGE
#undef BUILD_AFRAG

  float linv[4];
#pragma unroll
  for (int r = 0; r < 4; ++r)
    linv[r] = 1.0f / fmaxf(__shfl(acc[4][r], lane & 48), 1e-35f);

#pragma unroll
  for (int nt = 0; nt < 4; ++nt)
#pragma unroll
    for (int r = 0; r < 4; ++r) {
      int t = qt * 64 + mw + g * 4 + r;
      att[((size_t)b * T_SEQ + t) * CDIM + h * 64 + nt * 16 + li] =
          __float2bfloat16(acc[nt][r] * linv[r]);
    }
}

// ---------------- launch ----------------
extern "C" void kernel_launch(void* const* d_in, const int* in_sizes, int n_in,
                              void* d_out, int out_size, void* d_ws, size_t ws_size,
                              hipStream_t stream) {
  const float* x  = (const float*)d_in[0];
  const float* wq = (const float*)d_in[1];
  const float* wk = (const float*)d_in[2];
  const float* wv = (const float*)d_in[3];
  const float* wo = (const float*)d_in[4];
  const float* hd = (const float*)d_in[5];
  const float* sc = (const float*)d_in[6];
  float* out = (float*)d_out;

  char* ws = (char*)d_ws;
  bf16_t* wqkT = (bf16_t*)(ws + 0);          // 96*1024*2      = 196608
  bf16_t* wvT  = (bf16_t*)(ws + 196608);     // 1024*1024*2    = 2097152
  bf16_t* woT  = (bf16_t*)(ws + 2293760);    // 1024*1024*2
  float*  Qt   = (float*)(ws + 4390912);     // 3*32*2048*4    = 786432
  float*  Kt   = (float*)(ws + 5177344);     // 786432
  bf16_t* VT   = (bf16_t*)(ws + 5963776);    // 32*64*2048*2   = 8388608
  bf16_t* att  = (bf16_t*)(ws + 14352384);   // 4096*1024*2    = 8388608
  bf16_t* xb   = (bf16_t*)(ws + 22740992);   // 4096*1024*2    = 8388608

  k_prep<<<5248, 256, 0, stream>>>(x, wq, wk, wv, xb, wqkT, wvT);

  // blocks 0..255: QK projection; blocks 256..767: VT GEMM
  // VT[vdim][b,t] = sum_k wvT[vdim][k] * xb[b,t][k]
  k_gemmqk<<<768, 256, 0, stream>>>(wvT, xb, VT, 1024, 4096, 1024, 0, 32, 1,
                                    xb, wqkT, hd, sc, Qt, Kt);

  // blocks 0..1023: attention; blocks 1024..2047: wo transpose (for gemm2)
  k_attn<<<2048, 256, 0, stream>>>(Qt, Kt, VT, att, wo, woT);

  // out = att @ wo (fp32 out)
  k_gemmqk<<<512, 256, 0, stream>>>(att, woT, out, 4096, 1024, 1024, 1, 8, 0,
                                    nullptr, nullptr, nullptr, nullptr, nullptr, nullptr);
}

// Round 14
// 145.165 us; speedup vs baseline: 1.0463x; 1.0229x over previous
//
#include <hip/hip_runtime.h>
#include <hip/hip_bf16.h>

// GeometricAttention on MI355X (gfx950).
// B=2, T=2048, C=1024, H=16, hd=64, QK-dim=3.
// d_in are float*, d_out is float*. Internally bf16 MFMA (fp32 accumulate).
// R19: R18's hand cvt_pk REVERTED (failed correctness; m240 was right --
//      compiler's cast is fine, cast micro-opt closed). Attn restored to
//      R17 verbatim (verified 148.5us). New: T1 XCD patch-blocking on both
//      GEMMs -- map each XCD (gb&7 under round-robin dispatch) to an 8x8
//      (by,bx) patch so its working set (8 A-panels + 8 B-panels ~ 3MB)
//      fits the 4MB per-XCD L2; tile re-reads become L2 hits instead of
//      L3 round-trips. Bijective map -> correctness independent of the
//      actual XCD assignment.

typedef short bf16x8 __attribute__((ext_vector_type(8)));
typedef float f32x4 __attribute__((ext_vector_type(4)));
typedef __hip_bfloat16 bf16_t;
typedef unsigned int __attribute__((address_space(1))) u32_as1;
typedef unsigned int __attribute__((address_space(3))) u32_as3;

#define T_SEQ 2048
#define NHEAD 16
#define CDIM 1024
#define L2E 1.4426950408889634f

__device__ __forceinline__ void gl_lds16(const void* g, void* l) {
  __builtin_amdgcn_global_load_lds((const u32_as1*)g, (u32_as3*)l, 16, 0, 0);
}

__device__ __forceinline__ f32x4 mfma16(bf16x8 a, bf16x8 b, f32x4 c) {
  return __builtin_amdgcn_mfma_f32_16x16x32_bf16(a, b, c, 0, 0, 0);
}

__device__ __forceinline__ unsigned short f2bf(float f) {
  __hip_bfloat16 h = __float2bfloat16(f);
  return *(unsigned short*)&h;
}

__device__ __forceinline__ float fast_exp2(float x) {
#if __has_builtin(__builtin_amdgcn_exp2f)
  return __builtin_amdgcn_exp2f(x);
#else
  return exp2f(x);
#endif
}

// ---------------- fused prep: cast x -> xb, transpose+cast wv/wq/wk ----------------
// blocks 0..4095: cast (4 float4/thread); 4096..5119: wv; 5120..5183: wq;
// 5184..5247: wk.  (wo transpose lives in the k_attn launch.)
__global__ __launch_bounds__(256) void k_prep(const float* __restrict__ x,
                                              const float* __restrict__ wq,
                                              const float* __restrict__ wk,
                                              const float* __restrict__ wv,
                                              bf16_t* __restrict__ xb,
                                              bf16_t* __restrict__ wqkT,
                                              bf16_t* __restrict__ wvT) {
  __shared__ bf16_t tile[32][33];
  int bid = blockIdx.x, tid = threadIdx.x;
  if (bid < 4096) {
    int i = bid * 256 + tid;
    float4 v = ((const float4*)x)[i];
    ushort4 o;
    o.x = f2bf(v.x); o.y = f2bf(v.y); o.z = f2bf(v.z); o.w = f2bf(v.w);
    ((ushort4*)xb)[i] = o;
    return;
  }
  const float* src; bf16_t* dst; int R, C, bx, by;
  if (bid < 5120)      { int t = bid - 4096; src = wv; dst = wvT;            R = 1024; C = 1024; bx = t & 31; by = t >> 5; }
  else if (bid < 5184) { int t = bid - 5120; src = wq; dst = wqkT;           R = 1024; C = 48;   bx = t & 1;  by = t >> 1; }
  else                 { int t = bid - 5184; src = wk; dst = wqkT + 48*1024; R = 1024; C = 48;   bx = t & 1;  by = t >> 1; }
  int tx = tid & 31, ty = tid >> 5;
  int r0 = by * 32, c0 = bx * 32;
#pragma unroll
  for (int j = 0; j < 32; j += 8) {
    int r = r0 + ty + j, c = c0 + tx;
    if (r < R && c < C) tile[ty + j][tx] = __float2bfloat16(src[(size_t)r * C + c]);
  }
  __syncthreads();
#pragma unroll
  for (int j = 0; j < 32; j += 8) {
    int c = c0 + ty + j, r = r0 + tx;
    if (r < R && c < C) dst[(size_t)c * R + r] = tile[tx][ty + j];
  }
}

// ---------------- fused GEMM (+ optional QK projection) ----------------
// GEMM: 64x128x64 tile, double-buffered LDS (two 32-wide slabs per buffer),
//   stage(k+1) issued before compute(k), one __syncthreads per K-step
//   (16 barriers). Identical loop to the R8/R10/R15 harness-verified one.
//   Block->tile map: XCD patch-blocking (see R19 header). 512 gemm blocks,
//   xcd = gb&7, idx = gb>>3; patch grid = (8/pcols) x pcols with
//   pcols = nbx/8; by = (xcd/pcols)*8 + idx/8, bx = (xcd%pcols)*8 + idx%8.
// fuse_qk=1: blocks [0,256) run the QK projection (reads xb/wqkT, writes
//   Qt/Kt pre-scaled by log2e), blocks [256,...) run the GEMM.
__global__ __launch_bounds__(256) void k_gemmqk(const bf16_t* __restrict__ A,
                                                const bf16_t* __restrict__ Bt,
                                                void* __restrict__ Cout,
                                                int M, int N, int K, int mode,
                                                int nbx, int fuse_qk,
                                                const bf16_t* __restrict__ xb,
                                                const bf16_t* __restrict__ wqkT,
                                                const float* __restrict__ head_dirs,
                                                const float* __restrict__ scale,
                                                float* __restrict__ Qt,
                                                float* __restrict__ Kt) {
  __shared__ union SMem {
    struct {
      alignas(16) bf16_t A[2][2 * 64 * 32];   // 16 KB
      alignas(16) bf16_t B[2][2 * 128 * 32];  // 32 KB
    } g;
    float red[4][16][96];  // 24 KB
  } sm;
  int tid = threadIdx.x, wave = tid >> 6, lane = tid & 63;
  int g = lane >> 4, li = lane & 15;

  if (fuse_qk && blockIdx.x < 256) {
    // ---- QK projection path (M=4096, N=96, K=1024), split-K x4 ----
    int m0 = blockIdx.x * 16;
    f32x4 acc[6] = {};
    int kb = wave * 256;
    for (int k0 = kb; k0 < kb + 256; k0 += 32) {
      bf16x8 a = *(const bf16x8*)(xb + (size_t)(m0 + li) * 1024 + k0 + g * 8);
#pragma unroll
      for (int nt = 0; nt < 6; ++nt) {
        bf16x8 bb = *(const bf16x8*)(wqkT + (size_t)(nt * 16 + li) * 1024 + k0 + g * 8);
        acc[nt] = mfma16(a, bb, acc[nt]);
      }
    }
#pragma unroll
    for (int nt = 0; nt < 6; ++nt)
#pragma unroll
      for (int r = 0; r < 4; ++r) sm.red[wave][g * 4 + r][nt * 16 + li] = acc[nt][r];
    __syncthreads();
    for (int i = tid; i < 16 * 96; i += 256) {
      int row = i / 96, col = i - (i / 96) * 96;
      float v = sm.red[0][row][col] + sm.red[1][row][col] + sm.red[2][row][col] + sm.red[3][row][col];
      if (col >= 48) {
        int n = col - 48;
        int h = n / 3, c = n - h * 3;
        int mg = m0 + row;
        int bb = mg >> 11, tt = mg & 2047;
        Kt[(((size_t)bb * NHEAD + h) * 3 + c) * T_SEQ + tt] = v;
      } else {
        sm.red[0][row][col] = v;
      }
    }
    __syncthreads();
    int row = tid >> 4, h = tid & 15;
    float q0 = sm.red[0][row][h * 3 + 0];
    float q1 = sm.red[0][row][h * 3 + 1];
    float q2 = sm.red[0][row][h * 3 + 2];
    float d0 = head_dirs[h * 3 + 0];
    float d1 = head_dirs[h * 3 + 1];
    float d2 = head_dirs[h * 3 + 2];
    float sc = scale[0] * L2E;
    float dot = (q0 * d0 + q1 * d1 + q2 * d2) * L2E;
    int mg = m0 + row;
    int bb = mg >> 11, tt = mg & 2047;
    size_t base = ((size_t)bb * NHEAD + h) * 3 * T_SEQ + tt;
    Qt[base] = sc * q0 + d0 * dot;
    Qt[base + T_SEQ] = sc * q1 + d1 * dot;
    Qt[base + 2 * T_SEQ] = sc * q2 + d2 * dot;
    return;
  }

  // ---- GEMM path (R8/R10-verified double-buffered loop) ----
  int gb = blockIdx.x - (fuse_qk ? 256 : 0);
  // XCD patch-blocking: per-XCD working set = 8 A-panels + 8 B-panels ~3MB
  // (fits 4MB per-XCD L2). Bijective for 512 blocks, nbx in {8,32}.
  int xcd = gb & 7, idx = gb >> 3;
  int pcols = nbx >> 3;                       // gemm1: 4, gemm2: 1
  int pr = xcd / pcols, pc = xcd - pr * pcols;
  int by = pr * 8 + (idx >> 3);
  int bx = pc * 8 + (idx & 7);
  int n0 = bx * 128, m0 = by * 64;
  int wm = wave >> 1, wn = wave & 1;

  const bf16_t* gA0 = A + (size_t)(m0 + (tid >> 2)) * K + (tid & 3) * 8;
  const bf16_t* gB0 = Bt + (size_t)(n0 + (tid >> 2)) * K + (tid & 3) * 8;
  const bf16_t* gB1 = Bt + (size_t)(n0 + 64 + (tid >> 2)) * K + (tid & 3) * 8;

#define GSTAGE(bufi, kk)                                          \
  {                                                               \
    char* aB = (char*)&sm.g.A[bufi][0];                           \
    char* bB = (char*)&sm.g.B[bufi][0];                           \
    gl_lds16(gA0 + (kk), aB + tid * 16);                          \
    gl_lds16(gA0 + (kk) + 32, aB + (256 + tid) * 16);             \
    gl_lds16(gB0 + (kk), bB + tid * 16);                          \
    gl_lds16(gB1 + (kk), bB + (256 + tid) * 16);                  \
    gl_lds16(gB0 + (kk) + 32, bB + (512 + tid) * 16);             \
    gl_lds16(gB1 + (kk) + 32, bB + (768 + tid) * 16);             \
  }

  f32x4 acc[2][4] = {};
  GSTAGE(0, 0);

  for (int k0 = 0; k0 < K; k0 += 64) {
    int cur = (k0 >> 6) & 1;
    __syncthreads();  // drains vmcnt: buf[cur] ready; frees buf[cur^1]
    if (k0 + 64 < K) GSTAGE(cur ^ 1, k0 + 64);
#pragma unroll
    for (int kk = 0; kk < 2; ++kk) {
      bf16x8 af[2], bfr[4];
#pragma unroll
      for (int mt = 0; mt < 2; ++mt)
        af[mt] = *(const bf16x8*)&sm.g.A[cur][kk * 2048 + (wm * 32 + mt * 16 + li) * 32 + g * 8];
#pragma unroll
      for (int nt = 0; nt < 4; ++nt)
        bfr[nt] = *(const bf16x8*)&sm.g.B[cur][kk * 4096 + (wn * 64 + nt * 16 + li) * 32 + g * 8];
#pragma unroll
      for (int mt = 0; mt < 2; ++mt)
#pragma unroll
        for (int nt = 0; nt < 4; ++nt)
          acc[mt][nt] = mfma16(af[mt], bfr[nt], acc[mt][nt]);
    }
  }
#undef GSTAGE

#pragma unroll
  for (int mt = 0; mt < 2; ++mt)
#pragma unroll
    for (int nt = 0; nt < 4; ++nt)
#pragma unroll
      for (int r = 0; r < 4; ++r) {
        int m = m0 + wm * 32 + mt * 16 + g * 4 + r;
        int n = n0 + wn * 64 + nt * 16 + li;
        float v = acc[mt][nt][r];
        if (mode == 0) {
          int bb = n >> 11, tt = n & 2047;
          ((bf16_t*)Cout)[((size_t)bb * 1024 + m) * T_SEQ + tt] = __float2bfloat16(v);
        } else {
          ((float*)Cout)[(size_t)m * N + n] = v;
        }
      }
}

// ---------------- attention (+ wo transpose in tail blocks) ----------------
// blocks 0..1023: attention; blocks 1024..2047: wo transpose (for gemm2).
// attn: block = 256 thr (4 waves), one (b,h) x 64-query tile; wave = 16 q.
// KVBLK=64, LDS ~20KB -> 6 blocks/CU (launch_bounds(256,6)).
// V staged global->LDS async (XOR-swizzled chunks, 2/thread), K staged by
// wave 3 (48 chunks). exp2-domain scores, double-buffered, rowsums via
// ones B-frag, balanced qt map, setprio(1) on PV MFMA cluster.
__global__ __launch_bounds__(256, 6) void k_attn(const float* __restrict__ Qt,
                                                 const float* __restrict__ Kt,
                                                 const bf16_t* __restrict__ VT,
                                                 bf16_t* __restrict__ att,
                                                 const float* __restrict__ wo,
                                                 bf16_t* __restrict__ woT) {
  __shared__ alignas(16) bf16_t Vb[2][64 * 64];  // [buf] 16 KB
  __shared__ alignas(16) float Ks[2][3 * 64];    // [buf] 1.5 KB
  __shared__ bf16_t trt[32][33];                 // transpose path only
  int tid = threadIdx.x, wave = tid >> 6, lane = tid & 63;
  int g = lane >> 4, li = lane & 15;
  int bid = blockIdx.x;

  if (bid >= 1024) {
    // ---- wo transpose path ----
    int t = bid - 1024;
    int bx = t & 31, by = t >> 5;
    int tx = tid & 31, ty = tid >> 5;
    int r0 = by * 32, c0 = bx * 32;
#pragma unroll
    for (int j = 0; j < 32; j += 8)
      trt[ty + j][tx] = __float2bfloat16(wo[(size_t)(r0 + ty + j) * 1024 + c0 + tx]);
    __syncthreads();
#pragma unroll
    for (int j = 0; j < 32; j += 8)
      woT[(size_t)(c0 + ty + j) * 1024 + r0 + tx] = trt[tx][ty + j];
    return;
  }

  int p = bid >> 5, bh = bid & 31;
  int a = p & 7, bq = p >> 3;
  int qt = (bq == 0) ? a : (bq == 1) ? 31 - a : (bq == 2) ? 8 + a : 23 - a;
  int b = bh >> 4, h = bh & 15;
  int mw = wave * 16;

  const float* Qp = Qt + (size_t)bh * 3 * T_SEQ;
  const float* Kp = Kt + (size_t)bh * 3 * T_SEQ;
  const bf16_t* Vp = VT + (size_t)bh * 64 * T_SEQ;

  int tq = qt * 64 + mw + li;
  float q0 = Qp[tq], q1 = Qp[T_SEQ + tq], q2 = Qp[2 * T_SEQ + tq];

  bf16x8 bones;  // B[n=li][k]=1 iff li==0 -> D[:,0] = rowsum
  unsigned short ob = (li == 0) ? (unsigned short)0x3F80 : (unsigned short)0;
#pragma unroll
  for (int j = 0; j < 8; ++j) bones[j] = (short)ob;

  // per-thread global V chunk pointers (chunk swizzle on the global side):
  // 64-key tile = 64 d-rows x 8 chunks = 512 chunks; thread covers
  // P = p*256 + wave*64 + lane (p=0,1): row d=P>>3, phys slot P&7,
  // logical chunk = (P&7) ^ (d&7); global addr = row d, logical chunk.
  const bf16_t* vg[2];
  int vofs[2];
#pragma unroll
  for (int pp = 0; pp < 2; ++pp) {
    int P = pp * 256 + wave * 64 + lane;
    int d = P >> 3, c = (P & 7) ^ (d & 7);
    vg[pp] = Vp + (size_t)d * T_SEQ + c * 8;
    vofs[pp] = P * 16;
  }
  // K tile staging: 3 rows x 64 f32 = 48 chunks of 16B; wave 3, lane<48:
  // chunk lane -> row lane>>4, col (lane&15)*4.
  const float* kg = Kp + (size_t)(lane >> 4) * T_SEQ + (lane & 15) * 4;

#define STAGE(bufi, s0v)                                                      \
  {                                                                           \
    gl_lds16(vg[0] + (s0v), (char*)&Vb[bufi][0] + vofs[0]);                   \
    gl_lds16(vg[1] + (s0v), (char*)&Vb[bufi][0] + vofs[1]);                   \
    if (wave == 3 && lane < 48)                                               \
      gl_lds16(kg + (s0v), (char*)&Ks[bufi][0] + lane * 16);                  \
  }

#define BUILD_AFRAG(MASKED)                                                   \
  _Pragma("unroll") for (int half = 0; half < 2; ++half) {                    \
    int kb = half * 32 + g * 8;                                               \
    f32x4 kv[3][2];                                                           \
    _Pragma("unroll") for (int c = 0; c < 3; ++c) {                           \
      kv[c][0] = *(const f32x4*)(ks + c * 64 + kb);                           \
      kv[c][1] = *(const f32x4*)(ks + c * 64 + kb + 4);                       \
    }                                                                         \
    _Pragma("unroll") for (int j = 0; j < 8; ++j) {                           \
      float scv = q0 * kv[0][j >> 2][j & 3] + q1 * kv[1][j >> 2][j & 3] +     \
                  q2 * kv[2][j >> 2][j & 3];                                  \
      float pv = fast_exp2(fminf(scv, 115.4f));                               \
      if (MASKED && (bkg + half * 32 + g * 8 + j > tq)) pv = 0.0f;            \
      afrag[half][j] = (short)f2bf(pv);                                       \
    }                                                                         \
  }

  int NT = qt + 1;  // 64-key tiles
  STAGE(0, 0);

  f32x4 acc[5] = {};
  int sw = li & 7;

  for (int st = 0; st < NT; ++st) {
    int buf = st & 1;
    __syncthreads();  // drains vmcnt (tile st ready) + frees buf^1
    if (st + 1 < NT) STAGE(buf ^ 1, (st + 1) * 64);
    const float* ks = &Ks[buf][0];
    int bkg = st * 64;
    bf16x8 afrag[2];
    if (st == qt) { BUILD_AFRAG(1) } else { BUILD_AFRAG(0) }
    const bf16_t* vb = &Vb[buf][0];
    __builtin_amdgcn_s_setprio(1);
#pragma unroll
    for (int nt = 0; nt < 4; ++nt) {
      int row = nt * 16 + li;
      bf16x8 b0 = *(const bf16x8*)&vb[row * 64 + (g ^ sw) * 8];
      bf16x8 b1 = *(const bf16x8*)&vb[row * 64 + ((4 + g) ^ sw) * 8];
      acc[nt] = mfma16(afrag[0], b0, acc[nt]);
      acc[nt] = mfma16(afrag[1], b1, acc[nt]);
    }
    acc[4] = mfma16(afrag[0], bones, acc[4]);
    acc[4] = mfma16(afrag[1], bones, acc[4]);
    __builtin_amdgcn_s_setprio(0);
  }
#undef STAGE
#undef BUILD_AFRAG

  float linv[4];
#pragma unroll
  for (int r = 0; r < 4; ++r)
    linv[r] = 1.0f / fmaxf(__shfl(acc[4][r], lane & 48), 1e-35f);

#pragma unroll
  for (int nt = 0; nt < 4; ++nt)
#pragma unroll
    for (int r = 0; r < 4; ++r) {
      int t = qt * 64 + mw + g * 4 + r;
      att[((size_t)b * T_SEQ + t) * CDIM + h * 64 + nt * 16 + li] =
          __float2bfloat16(acc[nt][r] * linv[r]);
    }
}

// ---------------- launch ----------------
extern "C" void kernel_launch(void* const* d_in, const int* in_sizes, int n_in,
                              void* d_out, int out_size, void* d_ws, size_t ws_size,
                              hipStream_t stream) {
  const float* x  = (const float*)d_in[0];
  const float* wq = (const float*)d_in[1];
  const float* wk = (const float*)d_in[2];
  const float* wv = (const float*)d_in[3];
  const float* wo = (const float*)d_in[4];
  const float* hd = (const float*)d_in[5];
  const float* sc = (const float*)d_in[6];
  float* out = (float*)d_out;

  char* ws = (char*)d_ws;
  bf16_t* wqkT = (bf16_t*)(ws + 0);          // 96*1024*2      = 196608
  bf16_t* wvT  = (bf16_t*)(ws + 196608);     // 1024*1024*2    = 2097152
  bf16_t* woT  = (bf16_t*)(ws + 2293760);    // 1024*1024*2
  float*  Qt   = (float*)(ws + 4390912);     // 3*32*2048*4    = 786432
  float*  Kt   = (float*)(ws + 5177344);     // 786432
  bf16_t* VT   = (bf16_t*)(ws + 5963776);    // 32*64*2048*2   = 8388608
  bf16_t* att  = (bf16_t*)(ws + 14352384);   // 4096*1024*2    = 8388608
  bf16_t* xb   = (bf16_t*)(ws + 22740992);   // 4096*1024*2    = 8388608

  k_prep<<<5248, 256, 0, stream>>>(x, wq, wk, wv, xb, wqkT, wvT);

  // blocks 0..255: QK projection; blocks 256..767: VT GEMM
  // VT[vdim][b,t] = sum_k wvT[vdim][k] * xb[b,t][k]
  k_gemmqk<<<768, 256, 0, stream>>>(wvT, xb, VT, 1024, 4096, 1024, 0, 32, 1,
                                    xb, wqkT, hd, sc, Qt, Kt);

  // blocks 0..1023: attention; blocks 1024..2047: wo transpose (for gemm2)
  k_attn<<<2048, 256, 0, stream>>>(Qt, Kt, VT, att, wo, woT);

  // out = att @ wo (fp32 out)
  k_gemmqk<<<512, 256, 0, stream>>>(att, woT, out, 4096, 1024, 1024, 1, 8, 0,
                                    nullptr, nullptr, nullptr, nullptr, nullptr, nullptr);
}

// Round 15
// 144.417 us; speedup vs baseline: 1.0518x; 1.0052x over previous
//
#include <hip/hip_runtime.h>
#include <hip/hip_bf16.h>

// GeometricAttention on MI355X (gfx950).
// B=2, T=2048, C=1024, H=16, hd=64, QK-dim=3.
// d_in are float*, d_out is float*. Internally bf16 MFMA (fp32 accumulate).
// R20: single change vs R19 (verified 145.2us): BUILD_AFRAG packs P-values
//      via the documented HIP intrinsic __float22bfloat162_rn (compiler-
//      lowered packed convert; RNE; correct lo/hi order -- unlike R18's
//      failed hand asm). If the scalar __float2bfloat16 was lowering to the
//      ~5-inst software sequence, this removes ~25% of attn's VALU issue;
//      if not, neutral. GEMM (XCD patch-blocked), qkproj fusion, KVBLK=64
//      attn, setprio, wo-tail: verbatim R19.

typedef short bf16x8 __attribute__((ext_vector_type(8)));
typedef float f32x4 __attribute__((ext_vector_type(4)));
typedef __hip_bfloat16 bf16_t;
typedef unsigned int __attribute__((address_space(1))) u32_as1;
typedef unsigned int __attribute__((address_space(3))) u32_as3;

#define T_SEQ 2048
#define NHEAD 16
#define CDIM 1024
#define L2E 1.4426950408889634f

__device__ __forceinline__ void gl_lds16(const void* g, void* l) {
  __builtin_amdgcn_global_load_lds((const u32_as1*)g, (u32_as3*)l, 16, 0, 0);
}

__device__ __forceinline__ f32x4 mfma16(bf16x8 a, bf16x8 b, f32x4 c) {
  return __builtin_amdgcn_mfma_f32_16x16x32_bf16(a, b, c, 0, 0, 0);
}

__device__ __forceinline__ unsigned short f2bf(float f) {
  __hip_bfloat16 h = __float2bfloat16(f);
  return *(unsigned short*)&h;
}

__device__ __forceinline__ float fast_exp2(float x) {
#if __has_builtin(__builtin_amdgcn_exp2f)
  return __builtin_amdgcn_exp2f(x);
#else
  return exp2f(x);
#endif
}

// ---------------- fused prep: cast x -> xb, transpose+cast wv/wq/wk ----------------
// blocks 0..4095: cast (4 float4/thread); 4096..5119: wv; 5120..5183: wq;
// 5184..5247: wk.  (wo transpose lives in the k_attn launch.)
__global__ __launch_bounds__(256) void k_prep(const float* __restrict__ x,
                                              const float* __restrict__ wq,
                                              const float* __restrict__ wk,
                                              const float* __restrict__ wv,
                                              bf16_t* __restrict__ xb,
                                              bf16_t* __restrict__ wqkT,
                                              bf16_t* __restrict__ wvT) {
  __shared__ bf16_t tile[32][33];
  int bid = blockIdx.x, tid = threadIdx.x;
  if (bid < 4096) {
    int i = bid * 256 + tid;
    float4 v = ((const float4*)x)[i];
    ushort4 o;
    o.x = f2bf(v.x); o.y = f2bf(v.y); o.z = f2bf(v.z); o.w = f2bf(v.w);
    ((ushort4*)xb)[i] = o;
    return;
  }
  const float* src; bf16_t* dst; int R, C, bx, by;
  if (bid < 5120)      { int t = bid - 4096; src = wv; dst = wvT;            R = 1024; C = 1024; bx = t & 31; by = t >> 5; }
  else if (bid < 5184) { int t = bid - 5120; src = wq; dst = wqkT;           R = 1024; C = 48;   bx = t & 1;  by = t >> 1; }
  else                 { int t = bid - 5184; src = wk; dst = wqkT + 48*1024; R = 1024; C = 48;   bx = t & 1;  by = t >> 1; }
  int tx = tid & 31, ty = tid >> 5;
  int r0 = by * 32, c0 = bx * 32;
#pragma unroll
  for (int j = 0; j < 32; j += 8) {
    int r = r0 + ty + j, c = c0 + tx;
    if (r < R && c < C) tile[ty + j][tx] = __float2bfloat16(src[(size_t)r * C + c]);
  }
  __syncthreads();
#pragma unroll
  for (int j = 0; j < 32; j += 8) {
    int c = c0 + ty + j, r = r0 + tx;
    if (r < R && c < C) dst[(size_t)c * R + r] = tile[tx][ty + j];
  }
}

// ---------------- fused GEMM (+ optional QK projection) ----------------
// GEMM: 64x128x64 tile, double-buffered LDS (two 32-wide slabs per buffer),
//   stage(k+1) issued before compute(k), one __syncthreads per K-step
//   (16 barriers). Identical loop to the R8/R10/R15 harness-verified one.
//   Block->tile map: XCD patch-blocking. 512 gemm blocks, xcd = gb&7,
//   idx = gb>>3; pcols = nbx/8; by = (xcd/pcols)*8 + idx/8,
//   bx = (xcd%pcols)*8 + idx%8. Per-XCD working set ~3MB < 4MB L2.
// fuse_qk=1: blocks [0,256) run the QK projection (reads xb/wqkT, writes
//   Qt/Kt pre-scaled by log2e), blocks [256,...) run the GEMM.
__global__ __launch_bounds__(256) void k_gemmqk(const bf16_t* __restrict__ A,
                                                const bf16_t* __restrict__ Bt,
                                                void* __restrict__ Cout,
                                                int M, int N, int K, int mode,
                                                int nbx, int fuse_qk,
                                                const bf16_t* __restrict__ xb,
                                                const bf16_t* __restrict__ wqkT,
                                                const float* __restrict__ head_dirs,
                                                const float* __restrict__ scale,
                                                float* __restrict__ Qt,
                                                float* __restrict__ Kt) {
  __shared__ union SMem {
    struct {
      alignas(16) bf16_t A[2][2 * 64 * 32];   // 16 KB
      alignas(16) bf16_t B[2][2 * 128 * 32];  // 32 KB
    } g;
    float red[4][16][96];  // 24 KB
  } sm;
  int tid = threadIdx.x, wave = tid >> 6, lane = tid & 63;
  int g = lane >> 4, li = lane & 15;

  if (fuse_qk && blockIdx.x < 256) {
    // ---- QK projection path (M=4096, N=96, K=1024), split-K x4 ----
    int m0 = blockIdx.x * 16;
    f32x4 acc[6] = {};
    int kb = wave * 256;
    for (int k0 = kb; k0 < kb + 256; k0 += 32) {
      bf16x8 a = *(const bf16x8*)(xb + (size_t)(m0 + li) * 1024 + k0 + g * 8);
#pragma unroll
      for (int nt = 0; nt < 6; ++nt) {
        bf16x8 bb = *(const bf16x8*)(wqkT + (size_t)(nt * 16 + li) * 1024 + k0 + g * 8);
        acc[nt] = mfma16(a, bb, acc[nt]);
      }
    }
#pragma unroll
    for (int nt = 0; nt < 6; ++nt)
#pragma unroll
      for (int r = 0; r < 4; ++r) sm.red[wave][g * 4 + r][nt * 16 + li] = acc[nt][r];
    __syncthreads();
    for (int i = tid; i < 16 * 96; i += 256) {
      int row = i / 96, col = i - (i / 96) * 96;
      float v = sm.red[0][row][col] + sm.red[1][row][col] + sm.red[2][row][col] + sm.red[3][row][col];
      if (col >= 48) {
        int n = col - 48;
        int h = n / 3, c = n - h * 3;
        int mg = m0 + row;
        int bb = mg >> 11, tt = mg & 2047;
        Kt[(((size_t)bb * NHEAD + h) * 3 + c) * T_SEQ + tt] = v;
      } else {
        sm.red[0][row][col] = v;
      }
    }
    __syncthreads();
    int row = tid >> 4, h = tid & 15;
    float q0 = sm.red[0][row][h * 3 + 0];
    float q1 = sm.red[0][row][h * 3 + 1];
    float q2 = sm.red[0][row][h * 3 + 2];
    float d0 = head_dirs[h * 3 + 0];
    float d1 = head_dirs[h * 3 + 1];
    float d2 = head_dirs[h * 3 + 2];
    float sc = scale[0] * L2E;
    float dot = (q0 * d0 + q1 * d1 + q2 * d2) * L2E;
    int mg = m0 + row;
    int bb = mg >> 11, tt = mg & 2047;
    size_t base = ((size_t)bb * NHEAD + h) * 3 * T_SEQ + tt;
    Qt[base] = sc * q0 + d0 * dot;
    Qt[base + T_SEQ] = sc * q1 + d1 * dot;
    Qt[base + 2 * T_SEQ] = sc * q2 + d2 * dot;
    return;
  }

  // ---- GEMM path (R8/R10-verified double-buffered loop) ----
  int gb = blockIdx.x - (fuse_qk ? 256 : 0);
  // XCD patch-blocking: bijective for 512 blocks, nbx in {8,32}.
  int xcd = gb & 7, idx = gb >> 3;
  int pcols = nbx >> 3;                       // gemm1: 4, gemm2: 1
  int pr = xcd / pcols, pc = xcd - pr * pcols;
  int by = pr * 8 + (idx >> 3);
  int bx = pc * 8 + (idx & 7);
  int n0 = bx * 128, m0 = by * 64;
  int wm = wave >> 1, wn = wave & 1;

  const bf16_t* gA0 = A + (size_t)(m0 + (tid >> 2)) * K + (tid & 3) * 8;
  const bf16_t* gB0 = Bt + (size_t)(n0 + (tid >> 2)) * K + (tid & 3) * 8;
  const bf16_t* gB1 = Bt + (size_t)(n0 + 64 + (tid >> 2)) * K + (tid & 3) * 8;

#define GSTAGE(bufi, kk)                                          \
  {                                                               \
    char* aB = (char*)&sm.g.A[bufi][0];                           \
    char* bB = (char*)&sm.g.B[bufi][0];                           \
    gl_lds16(gA0 + (kk), aB + tid * 16);                          \
    gl_lds16(gA0 + (kk) + 32, aB + (256 + tid) * 16);             \
    gl_lds16(gB0 + (kk), bB + tid * 16);                          \
    gl_lds16(gB1 + (kk), bB + (256 + tid) * 16);                  \
    gl_lds16(gB0 + (kk) + 32, bB + (512 + tid) * 16);             \
    gl_lds16(gB1 + (kk) + 32, bB + (768 + tid) * 16);             \
  }

  f32x4 acc[2][4] = {};
  GSTAGE(0, 0);

  for (int k0 = 0; k0 < K; k0 += 64) {
    int cur = (k0 >> 6) & 1;
    __syncthreads();  // drains vmcnt: buf[cur] ready; frees buf[cur^1]
    if (k0 + 64 < K) GSTAGE(cur ^ 1, k0 + 64);
#pragma unroll
    for (int kk = 0; kk < 2; ++kk) {
      bf16x8 af[2], bfr[4];
#pragma unroll
      for (int mt = 0; mt < 2; ++mt)
        af[mt] = *(const bf16x8*)&sm.g.A[cur][kk * 2048 + (wm * 32 + mt * 16 + li) * 32 + g * 8];
#pragma unroll
      for (int nt = 0; nt < 4; ++nt)
        bfr[nt] = *(const bf16x8*)&sm.g.B[cur][kk * 4096 + (wn * 64 + nt * 16 + li) * 32 + g * 8];
#pragma unroll
      for (int mt = 0; mt < 2; ++mt)
#pragma unroll
        for (int nt = 0; nt < 4; ++nt)
          acc[mt][nt] = mfma16(af[mt], bfr[nt], acc[mt][nt]);
    }
  }
#undef GSTAGE

#pragma unroll
  for (int mt = 0; mt < 2; ++mt)
#pragma unroll
    for (int nt = 0; nt < 4; ++nt)
#pragma unroll
      for (int r = 0; r < 4; ++r) {
        int m = m0 + wm * 32 + mt * 16 + g * 4 + r;
        int n = n0 + wn * 64 + nt * 16 + li;
        float v = acc[mt][nt][r];
        if (mode == 0) {
          int bb = n >> 11, tt = n & 2047;
          ((bf16_t*)Cout)[((size_t)bb * 1024 + m) * T_SEQ + tt] = __float2bfloat16(v);
        } else {
          ((float*)Cout)[(size_t)m * N + n] = v;
        }
      }
}

// ---------------- attention (+ wo transpose in tail blocks) ----------------
// blocks 0..1023: attention; blocks 1024..2047: wo transpose (for gemm2).
// attn: block = 256 thr (4 waves), one (b,h) x 64-query tile; wave = 16 q.
// KVBLK=64, LDS ~20KB -> 6 blocks/CU (launch_bounds(256,6)).
// V staged global->LDS async (XOR-swizzled chunks, 2/thread), K staged by
// wave 3 (48 chunks). exp2-domain scores; P->bf16 via __float22bfloat162_rn
// (packed convert). Double-buffered, rowsums via ones B-frag, balanced qt
// map, setprio(1) on PV MFMA cluster.
__global__ __launch_bounds__(256, 6) void k_attn(const float* __restrict__ Qt,
                                                 const float* __restrict__ Kt,
                                                 const bf16_t* __restrict__ VT,
                                                 bf16_t* __restrict__ att,
                                                 const float* __restrict__ wo,
                                                 bf16_t* __restrict__ woT) {
  __shared__ alignas(16) bf16_t Vb[2][64 * 64];  // [buf] 16 KB
  __shared__ alignas(16) float Ks[2][3 * 64];    // [buf] 1.5 KB
  __shared__ bf16_t trt[32][33];                 // transpose path only
  int tid = threadIdx.x, wave = tid >> 6, lane = tid & 63;
  int g = lane >> 4, li = lane & 15;
  int bid = blockIdx.x;

  if (bid >= 1024) {
    // ---- wo transpose path ----
    int t = bid - 1024;
    int bx = t & 31, by = t >> 5;
    int tx = tid & 31, ty = tid >> 5;
    int r0 = by * 32, c0 = bx * 32;
#pragma unroll
    for (int j = 0; j < 32; j += 8)
      trt[ty + j][tx] = __float2bfloat16(wo[(size_t)(r0 + ty + j) * 1024 + c0 + tx]);
    __syncthreads();
#pragma unroll
    for (int j = 0; j < 32; j += 8)
      woT[(size_t)(c0 + ty + j) * 1024 + r0 + tx] = trt[tx][ty + j];
    return;
  }

  int p = bid >> 5, bh = bid & 31;
  int a = p & 7, bq = p >> 3;
  int qt = (bq == 0) ? a : (bq == 1) ? 31 - a : (bq == 2) ? 8 + a : 23 - a;
  int b = bh >> 4, h = bh & 15;
  int mw = wave * 16;

  const float* Qp = Qt + (size_t)bh * 3 * T_SEQ;
  const float* Kp = Kt + (size_t)bh * 3 * T_SEQ;
  const bf16_t* Vp = VT + (size_t)bh * 64 * T_SEQ;

  int tq = qt * 64 + mw + li;
  float q0 = Qp[tq], q1 = Qp[T_SEQ + tq], q2 = Qp[2 * T_SEQ + tq];

  bf16x8 bones;  // B[n=li][k]=1 iff li==0 -> D[:,0] = rowsum
  unsigned short ob = (li == 0) ? (unsigned short)0x3F80 : (unsigned short)0;
#pragma unroll
  for (int j = 0; j < 8; ++j) bones[j] = (short)ob;

  // per-thread global V chunk pointers (chunk swizzle on the global side):
  // 64-key tile = 64 d-rows x 8 chunks = 512 chunks; thread covers
  // P = p*256 + wave*64 + lane (p=0,1): row d=P>>3, phys slot P&7,
  // logical chunk = (P&7) ^ (d&7); global addr = row d, logical chunk.
  const bf16_t* vg[2];
  int vofs[2];
#pragma unroll
  for (int pp = 0; pp < 2; ++pp) {
    int P = pp * 256 + wave * 64 + lane;
    int d = P >> 3, c = (P & 7) ^ (d & 7);
    vg[pp] = Vp + (size_t)d * T_SEQ + c * 8;
    vofs[pp] = P * 16;
  }
  // K tile staging: 3 rows x 64 f32 = 48 chunks of 16B; wave 3, lane<48:
  // chunk lane -> row lane>>4, col (lane&15)*4.
  const float* kg = Kp + (size_t)(lane >> 4) * T_SEQ + (lane & 15) * 4;

#define STAGE(bufi, s0v)                                                      \
  {                                                                           \
    gl_lds16(vg[0] + (s0v), (char*)&Vb[bufi][0] + vofs[0]);                   \
    gl_lds16(vg[1] + (s0v), (char*)&Vb[bufi][0] + vofs[1]);                   \
    if (wave == 3 && lane < 48)                                               \
      gl_lds16(kg + (s0v), (char*)&Ks[bufi][0] + lane * 16);                  \
  }

#define BUILD_AFRAG(MASKED)                                                   \
  _Pragma("unroll") for (int half = 0; half < 2; ++half) {                    \
    int kb = half * 32 + g * 8;                                               \
    f32x4 kv[3][2];                                                           \
    _Pragma("unroll") for (int c = 0; c < 3; ++c) {                           \
      kv[c][0] = *(const f32x4*)(ks + c * 64 + kb);                           \
      kv[c][1] = *(const f32x4*)(ks + c * 64 + kb + 4);                       \
    }                                                                         \
    float pv[8];                                                              \
    _Pragma("unroll") for (int j = 0; j < 8; ++j) {                           \
      float scv = q0 * kv[0][j >> 2][j & 3] + q1 * kv[1][j >> 2][j & 3] +     \
                  q2 * kv[2][j >> 2][j & 3];                                  \
      float t = fast_exp2(fminf(scv, 115.4f));                                \
      if (MASKED && (bkg + half * 32 + g * 8 + j > tq)) t = 0.0f;             \
      pv[j] = t;                                                              \
    }                                                                         \
    _Pragma("unroll") for (int i = 0; i < 4; ++i)                             \
      au[half].h[i] = __float22bfloat162_rn(make_float2(pv[2 * i],            \
                                                        pv[2 * i + 1]));     \
  }

  int NT = qt + 1;  // 64-key tiles
  STAGE(0, 0);

  f32x4 acc[5] = {};
  int sw = li & 7;

  union AU { __hip_bfloat162 h[4]; bf16x8 v; };

  for (int st = 0; st < NT; ++st) {
    int buf = st & 1;
    __syncthreads();  // drains vmcnt (tile st ready) + frees buf^1
    if (st + 1 < NT) STAGE(buf ^ 1, (st + 1) * 64);
    const float* ks = &Ks[buf][0];
    int bkg = st * 64;
    AU au[2];
    if (st == qt) { BUILD_AFRAG(1) } else { BUILD_AFRAG(0) }
    const bf16_t* vb = &Vb[buf][0];
    __builtin_amdgcn_s_setprio(1);
#pragma unroll
    for (int nt = 0; nt < 4; ++nt) {
      int row = nt * 16 + li;
      bf16x8 b0 = *(const bf16x8*)&vb[row * 64 + (g ^ sw) * 8];
      bf16x8 b1 = *(const bf16x8*)&vb[row * 64 + ((4 + g) ^ sw) * 8];
      acc[nt] = mfma16(au[0].v, b0, acc[nt]);
      acc[nt] = mfma16(au[1].v, b1, acc[nt]);
    }
    acc[4] = mfma16(au[0].v, bones, acc[4]);
    acc[4] = mfma16(au[1].v, bones, acc[4]);
    __builtin_amdgcn_s_setprio(0);
  }
#undef STAGE
#undef BUILD_AFRAG

  float linv[4];
#pragma unroll
  for (int r = 0; r < 4; ++r)
    linv[r] = 1.0f / fmaxf(__shfl(acc[4][r], lane & 48), 1e-35f);

#pragma unroll
  for (int nt = 0; nt < 4; ++nt)
#pragma unroll
    for (int r = 0; r < 4; ++r) {
      int t = qt * 64 + mw + g * 4 + r;
      att[((size_t)b * T_SEQ + t) * CDIM + h * 64 + nt * 16 + li] =
          __float2bfloat16(acc[nt][r] * linv[r]);
    }
}

// ---------------- launch ----------------
extern "C" void kernel_launch(void* const* d_in, const int* in_sizes, int n_in,
                              void* d_out, int out_size, void* d_ws, size_t ws_size,
                              hipStream_t stream) {
  const float* x  = (const float*)d_in[0];
  const float* wq = (const float*)d_in[1];
  const float* wk = (const float*)d_in[2];
  const float* wv = (const float*)d_in[3];
  const float* wo = (const float*)d_in[4];
  const float* hd = (const float*)d_in[5];
  const float* sc = (const float*)d_in[6];
  float* out = (float*)d_out;

  char* ws = (char*)d_ws;
  bf16_t* wqkT = (bf16_t*)(ws + 0);          // 96*1024*2      = 196608
  bf16_t* wvT  = (bf16_t*)(ws + 196608);     // 1024*1024*2    = 2097152
  bf16_t* woT  = (bf16_t*)(ws + 2293760);    // 1024*1024*2
  float*  Qt   = (float*)(ws + 4390912);     // 3*32*2048*4    = 786432
  float*  Kt   = (float*)(ws + 5177344);     // 786432
  bf16_t* VT   = (bf16_t*)(ws + 5963776);    // 32*64*2048*2   = 8388608
  bf16_t* att  = (bf16_t*)(ws + 14352384);   // 4096*1024*2    = 8388608
  bf16_t* xb   = (bf16_t*)(ws + 22740992);   // 4096*1024*2    = 8388608

  k_prep<<<5248, 256, 0, stream>>>(x, wq, wk, wv, xb, wqkT, wvT);

  // blocks 0..255: QK projection; blocks 256..767: VT GEMM
  // VT[vdim][b,t] = sum_k wvT[vdim][k] * xb[b,t][k]
  k_gemmqk<<<768, 256, 0, stream>>>(wvT, xb, VT, 1024, 4096, 1024, 0, 32, 1,
                                    xb, wqkT, hd, sc, Qt, Kt);

  // blocks 0..1023: attention; blocks 1024..2047: wo transpose (for gemm2)
  k_attn<<<2048, 256, 0, stream>>>(Qt, Kt, VT, att, wo, woT);

  // out = att @ wo (fp32 out)
  k_gemmqk<<<512, 256, 0, stream>>>(att, woT, out, 4096, 1024, 1024, 1, 8, 0,
                                    nullptr, nullptr, nullptr, nullptr, nullptr, nullptr);
}